// Round 12
// baseline (58.731 us; speedup 1.0000x reference)
//
#include <hip/hip_runtime.h>
#include <hip/hip_bf16.h>
#include <math.h>

#define B 4096
#define D 1024

// ---- 8-phase 256^2 simexp geometry ----
#define BM2 256
#define BK2 64
#define NK2 (D / BK2)   // 16 K-tiles
#define NB2 (B / BM2)   // 16 -> grid 256 blocks

typedef float f32x4 __attribute__((ext_vector_type(4)));
typedef short s16x8 __attribute__((ext_vector_type(8)));

__device__ inline void gload_lds16(const void* g, void* l) {
    __builtin_amdgcn_global_load_lds(
        (const __attribute__((address_space(1))) void*)g,
        (__attribute__((address_space(3))) void*)l, 16, 0, 0);
}

// K0: fp32 -> bf16 convert; also zero denomsum/lblsum accumulators.
__global__ __launch_bounds__(256) void prep_kernel(const float* __restrict__ E,
                                                   unsigned short* __restrict__ Ebf,
                                                   float* __restrict__ denomsum,
                                                   float* __restrict__ lblsum) {
    int idx = blockIdx.x * 256 + threadIdx.x;
    if (blockIdx.x < 16) denomsum[idx] = 0.f;
    else if (blockIdx.x < 32) lblsum[idx - 4096] = 0.f;
    const float4* src = (const float4*)E;
    const int n4 = B * D / 4;
    for (int i = idx; i < n4; i += gridDim.x * 256) {
        float4 v = src[i];
        __hip_bfloat16 b0 = __float2bfloat16(v.x);
        __hip_bfloat16 b1 = __float2bfloat16(v.y);
        __hip_bfloat16 b2 = __float2bfloat16(v.z);
        __hip_bfloat16 b3 = __float2bfloat16(v.w);
        ushort4 o;
        o.x = *reinterpret_cast<unsigned short*>(&b0);
        o.y = *reinterpret_cast<unsigned short*>(&b1);
        o.z = *reinterpret_cast<unsigned short*>(&b2);
        o.w = *reinterpret_cast<unsigned short*>(&b3);
        *reinterpret_cast<ushort4*>(&Ebf[i * 4]) = o;
    }
}

// MFMA quadrant: AH selects A rows half, NIH selects B cols half.
template <int AH, int NIH>
__device__ inline void doQ(f32x4 acc[8][4], const s16x8 aq[4][2], const s16x8 bq[2][2][2]) {
    __builtin_amdgcn_s_setprio(1);
#pragma unroll
    for (int mi = 0; mi < 4; ++mi)
#pragma unroll
        for (int ni = 0; ni < 2; ++ni)
#pragma unroll
            for (int ks = 0; ks < 2; ++ks)
                acc[AH * 4 + mi][NIH * 2 + ni] = __builtin_amdgcn_mfma_f32_16x16x32_bf16(
                    aq[mi][ks], bq[NIH][ni][ks], acc[AH * 4 + mi][NIH * 2 + ni], 0, 0, 0);
    __builtin_amdgcn_s_setprio(0);
}

// K1: 256^2 8-phase simexp, intra-tile read-prefetch variant.
//   denomsum[i] += sum_j exp(sim[i,j])   (diag masked)
//   lblsum[i]   += sum_j sim[i,j] * [label_j == 0]   (diag INCLUDED)
//   selfsim[i]   = sim[i,i]
// LDS halves: 0=A rows 0-127, 1=A rows 128-255, 2=B rows 0-127, 3=B rows 128-255.
// XOR chunk swizzle on both global_load_lds source and ds_read addr.
// Stage schedule per tile u (UNCHANGED from R6-verified ledger):
//   P1:(u+1).A_lo  P2:(u+1).A_hi  P3:(u+2).B_lo  P4:(u+2).B_hi
// Read prefetch (NEW): B-q1 reads hoisted into P1, A-q1 reads into P2 (buffer aq2).
//   Safety: at tile start all 4 halves are vmcnt-landed; hoisted B reads drain
//   before each wave's P2-closing barrier, which precedes P3's stage into B slots;
//   A slots of buf bp are never written during tile u. No manual lgkmcnt — the
//   compiler emits counted waits per consumer, letting reads fly under MFMA.
// One counted vmcnt(4) per tile at P4; drains to 0 only at u=14.
__global__ __launch_bounds__(512, 2) void simexp8_kernel(const unsigned short* __restrict__ Ebf,
                                                         const int* __restrict__ labels,
                                                         float* __restrict__ denomsum,
                                                         float* __restrict__ lblsum,
                                                         float* __restrict__ selfsim) {
    __shared__ short lds[2][4][128 * 64];  // 128 KiB
    const int tid = threadIdx.x;
    const int lane = tid & 63;
    const int wave = tid >> 6;  // 0..7
    const int wm = wave >> 2;   // 0..1  (M half)
    const int wn = wave & 3;    // 0..3  (N quarter)
    const int kh = lane >> 4;   // 0..3
    const int lrow = lane & 15;
    const int bi = blockIdx.x >> 4;
    const int bj = blockIdx.x & 15;
    const int rowBase = bi * BM2;
    const int colBase = bj * BM2;

    const short* gbase = (const short*)Ebf;

    // stage half h of K-tile kt into buf (2 x global_load_lds per thread)
    auto stage = [&](int kt, int buf, int h) {
        int gr0 = (h < 2 ? rowBase : colBase) + ((h & 1) ? 128 : 0);
#pragma unroll
        for (int q = 0; q < 2; ++q) {
            int i = q * 512 + tid;       // 16B chunk index in half (0..1023)
            int r = i >> 3;              // row in half
            int lc = (i & 7) ^ (r & 7);  // logical chunk for this physical slot
            const short* g = gbase + (size_t)(gr0 + r) * D + kt * BK2 + lc * 8;
            gload_lds16(g, &lds[buf][h][i * 8]);
        }
    };

    auto ldA = [&](int buf, int ah, s16x8 (&a)[4][2]) {
#pragma unroll
        for (int mi = 0; mi < 4; ++mi)
#pragma unroll
            for (int ks = 0; ks < 2; ++ks) {
                int rh = ah * 64 + mi * 16 + lrow;
                int c = ks * 4 + kh;
                a[mi][ks] = *(const s16x8*)&lds[buf][wm][rh * 64 + ((c ^ (rh & 7)) << 3)];
            }
    };
    auto ldB = [&](int buf, int nih, s16x8 (&bf)[2][2]) {
        int h = 2 + (wn >> 1);
#pragma unroll
        for (int ni = 0; ni < 2; ++ni)
#pragma unroll
            for (int ks = 0; ks < 2; ++ks) {
                int rh = (wn & 1) * 64 + nih * 32 + ni * 16 + lrow;
                int c = ks * 4 + kh;
                bf[ni][ks] = *(const s16x8*)&lds[buf][h][rh * 64 + ((c ^ (rh & 7)) << 3)];
            }
    };

    f32x4 acc[8][4];
#pragma unroll
    for (int i = 0; i < 8; ++i)
#pragma unroll
        for (int j = 0; j < 4; ++j) acc[i][j] = (f32x4)(0.f);

    s16x8 aq[4][2];   // A-q0 fragments
    s16x8 aq2[4][2];  // A-q1 fragments (prefetched in P2)
    s16x8 bq[2][2][2];

    // prologue: tile0 all 4 halves + tile1 B halves; wait tile0, leave tile1.B flying
    stage(0, 0, 0);
    stage(0, 0, 1);
    stage(0, 0, 2);
    stage(0, 0, 3);
    stage(1, 1, 2);
    stage(1, 1, 3);
    asm volatile("s_waitcnt vmcnt(4)" ::: "memory");
    __builtin_amdgcn_s_barrier();

    for (int u = 0; u < NK2; ++u) {
        const int bp = u & 1;
        // ---- P1: read A-q0 (8) + B-q0 (4) + B-q1 (4, prefetch); stage (u+1).A_lo ----
        ldA(bp, 0, aq);
        ldB(bp, 0, bq[0]);
        ldB(bp, 1, bq[1]);  // prefetch: consumed in P2's MFMA
        if (u + 1 < NK2) stage(u + 1, bp ^ 1, 0);
        __builtin_amdgcn_s_barrier();
        doQ<0, 0>(acc, aq, bq);  // compiler-counted wait: aq + bq[0]; bq[1] flies
        __builtin_amdgcn_s_barrier();
        // ---- P2: read A-q1 (8, prefetch into aq2); stage (u+1).A_hi ----
        ldA(bp, 1, aq2);  // prefetch: consumed in P3's MFMA
        if (u + 1 < NK2) stage(u + 1, bp ^ 1, 1);
        __builtin_amdgcn_s_barrier();
        doQ<0, 1>(acc, aq, bq);  // compiler-counted wait: bq[1]; aq2 flies
        __builtin_amdgcn_s_barrier();
        // ---- P3: no reads; stage (u+2).B_lo ----
        if (u + 2 < NK2) stage(u + 2, bp, 2);
        __builtin_amdgcn_s_barrier();
        doQ<1, 1>(acc, aq2, bq);  // compiler wait drains aq2
        __builtin_amdgcn_s_barrier();
        // ---- P4 (reg-only MFMA): stage (u+2).B_hi; counted vmcnt; one barrier ----
        if (u + 2 < NK2) stage(u + 2, bp, 3);
        doQ<1, 0>(acc, aq2, bq);
        if (u + 2 < NK2) {
            asm volatile("s_waitcnt vmcnt(4)" ::: "memory");  // (u+1) fully landed; (u+2).B_* fly
        } else if (u + 1 < NK2) {
            asm volatile("s_waitcnt vmcnt(0)" ::: "memory");  // tail drain (u=14)
        }
        __builtin_amdgcn_s_barrier();
    }

    // epilogue: exp + diag mask -> denomsum; label-masked sim row-sum -> lblsum;
    // diagonal sim -> selfsim.
    float lbm[4];
#pragma unroll
    for (int ni = 0; ni < 4; ++ni)
        lbm[ni] = (labels[colBase + wn * 64 + ni * 16 + lrow] == 0) ? 1.f : 0.f;

#pragma unroll
    for (int mi = 0; mi < 8; ++mi) {
        float rs[4] = {0.f, 0.f, 0.f, 0.f};
        float ps[4] = {0.f, 0.f, 0.f, 0.f};
#pragma unroll
        for (int ni = 0; ni < 4; ++ni) {
            int gcol = colBase + wn * 64 + ni * 16 + lrow;
#pragma unroll
            for (int r = 0; r < 4; ++r) {
                int grow = rowBase + wm * 128 + mi * 16 + kh * 4 + r;
                float sv = acc[mi][ni][r];
                float e = __expf(sv);
                if (grow == gcol) {
                    e = 0.f;
                    selfsim[grow] = sv;
                }
                rs[r] += e;
                ps[r] += sv * lbm[ni];
            }
        }
#pragma unroll
        for (int m = 1; m < 16; m <<= 1)
#pragma unroll
            for (int r = 0; r < 4; ++r) {
                rs[r] += __shfl_xor(rs[r], m, 64);
                ps[r] += __shfl_xor(ps[r], m, 64);
            }
        if (lrow == 0) {
#pragma unroll
            for (int r = 0; r < 4; ++r) {
                int grow = rowBase + wm * 128 + mi * 16 + kh * 4 + r;
                atomicAdd(&denomsum[grow], rs[r]);
                atomicAdd(&lblsum[grow], ps[r]);
            }
        }
    }
}

// K2: finalize scalar loss.
__global__ __launch_bounds__(1024) void finalize_kernel(const int* __restrict__ labels,
                                                        const float* __restrict__ denomsum,
                                                        const float* __restrict__ lblsum,
                                                        const float* __restrict__ selfsim,
                                                        float* __restrict__ out) {
    __shared__ int ncnt[16];
    __shared__ float tsum[16];
    int tid = threadIdx.x;
    int wv = tid >> 6, ln = tid & 63;

    int cnt = 0;
    for (int j = tid; j < B; j += 1024) cnt += (labels[j] == 0) ? 1 : 0;
    for (int m = 32; m; m >>= 1) cnt += __shfl_xor(cnt, m, 64);
    if (ln == 0) ncnt[wv] = cnt;
    __syncthreads();
    int n_normal = 0;
#pragma unroll
    for (int w = 0; w < 16; ++w) n_normal += ncnt[w];

    float local = 0.f;
    for (int i = tid; i < B; i += 1024) {
        if (labels[i] == 0) {
            int cntp = n_normal - 1;
            if (cntp > 0) {
                float possum = lblsum[i] - selfsim[i];  // remove j==i term (label_i==0 here)
                local += logf(denomsum[i]) - possum / (float)cntp;
            }
        }
    }
    for (int m = 32; m; m >>= 1) local += __shfl_xor(local, m, 64);
    if (ln == 0) tsum[wv] = local;
    __syncthreads();
    if (tid == 0) {
        float t = 0.f;
#pragma unroll
        for (int w = 0; w < 16; ++w) t += tsum[w];
        out[0] = (n_normal > 0) ? t / (float)n_normal : 0.f;
    }
}

extern "C" void kernel_launch(void* const* d_in, const int* in_sizes, int n_in,
                              void* d_out, int out_size, void* d_ws, size_t ws_size,
                              hipStream_t stream) {
    const float* E = (const float*)d_in[0];
    const int* labels = (const int*)d_in[1];
    float* out = (float*)d_out;

    char* ws = (char*)d_ws;
    size_t off = 0;
    unsigned short* Ebf = (unsigned short*)(ws + off);
    off += (size_t)B * D * 2;  // 8 MB
    float* denomsum = (float*)(ws + off);
    off += B * sizeof(float);
    float* lblsum = (float*)(ws + off);
    off += B * sizeof(float);
    float* selfsim = (float*)(ws + off);
    off += B * sizeof(float);

    prep_kernel<<<2048, 256, 0, stream>>>(E, Ebf, denomsum, lblsum);
    simexp8_kernel<<<NB2 * NB2, 512, 0, stream>>>(Ebf, labels, denomsum, lblsum, selfsim);
    finalize_kernel<<<1, 1024, 0, stream>>>(labels, denomsum, lblsum, selfsim, out);
}

// Round 13
// 56.382 us; speedup vs baseline: 1.0416x; 1.0416x over previous
//
#include <hip/hip_runtime.h>
#include <hip/hip_bf16.h>
#include <math.h>

#define B 4096
#define D 1024

// ---- 8-phase 256^2 simexp geometry (R6-verified best configuration) ----
#define BM2 256
#define BK2 64
#define NK2 (D / BK2)   // 16 K-tiles
#define NB2 (B / BM2)   // 16 -> grid 256 blocks

typedef float f32x4 __attribute__((ext_vector_type(4)));
typedef short s16x8 __attribute__((ext_vector_type(8)));

__device__ inline void gload_lds16(const void* g, void* l) {
    __builtin_amdgcn_global_load_lds(
        (const __attribute__((address_space(1))) void*)g,
        (__attribute__((address_space(3))) void*)l, 16, 0, 0);
}

// K0: fp32 -> bf16 convert; also zero denomsum/lblsum accumulators.
__global__ __launch_bounds__(256) void prep_kernel(const float* __restrict__ E,
                                                   unsigned short* __restrict__ Ebf,
                                                   float* __restrict__ denomsum,
                                                   float* __restrict__ lblsum) {
    int idx = blockIdx.x * 256 + threadIdx.x;
    if (blockIdx.x < 16) denomsum[idx] = 0.f;
    else if (blockIdx.x < 32) lblsum[idx - 4096] = 0.f;
    const float4* src = (const float4*)E;
    const int n4 = B * D / 4;
    for (int i = idx; i < n4; i += gridDim.x * 256) {
        float4 v = src[i];
        __hip_bfloat16 b0 = __float2bfloat16(v.x);
        __hip_bfloat16 b1 = __float2bfloat16(v.y);
        __hip_bfloat16 b2 = __float2bfloat16(v.z);
        __hip_bfloat16 b3 = __float2bfloat16(v.w);
        ushort4 o;
        o.x = *reinterpret_cast<unsigned short*>(&b0);
        o.y = *reinterpret_cast<unsigned short*>(&b1);
        o.z = *reinterpret_cast<unsigned short*>(&b2);
        o.w = *reinterpret_cast<unsigned short*>(&b3);
        *reinterpret_cast<ushort4*>(&Ebf[i * 4]) = o;
    }
}

// MFMA quadrant: AH selects A rows half, NIH selects B cols half.
template <int AH, int NIH>
__device__ inline void doQ(f32x4 acc[8][4], const s16x8 aq[4][2], const s16x8 bq[2][2][2]) {
    __builtin_amdgcn_s_setprio(1);
#pragma unroll
    for (int mi = 0; mi < 4; ++mi)
#pragma unroll
        for (int ni = 0; ni < 2; ++ni)
#pragma unroll
            for (int ks = 0; ks < 2; ++ks)
                acc[AH * 4 + mi][NIH * 2 + ni] = __builtin_amdgcn_mfma_f32_16x16x32_bf16(
                    aq[mi][ks], bq[NIH][ni][ks], acc[AH * 4 + mi][NIH * 2 + ni], 0, 0, 0);
    __builtin_amdgcn_s_setprio(0);
}

// K1: 256^2 8-phase simexp.
//   denomsum[i] += sum_j exp(sim[i,j])   (diag masked)
//   lblsum[i]   += sum_j sim[i,j] * [label_j == 0]   (diag INCLUDED)
//   selfsim[i]   = sim[i,i]              (written by diagonal blocks)
// LDS halves: 0=A rows 0-127, 1=A rows 128-255, 2=B rows 0-127, 3=B rows 128-255.
// XOR chunk swizzle applied to global source (write side) and ds_read addr (read side).
// Stage schedule per tile u: P1:(u+1).A_lo  P2:(u+1).A_hi  P3:(u+2).B_lo  P4:(u+2).B_hi
//   (B halves are last read in P2, A halves in P3 -> each slot staged after its last reader.)
// One counted vmcnt(4) per tile at P4; drains to 0 only at u=14.
__global__ __launch_bounds__(512, 2) void simexp8_kernel(const unsigned short* __restrict__ Ebf,
                                                         const int* __restrict__ labels,
                                                         float* __restrict__ denomsum,
                                                         float* __restrict__ lblsum,
                                                         float* __restrict__ selfsim) {
    __shared__ short lds[2][4][128 * 64];  // 128 KiB
    const int tid = threadIdx.x;
    const int lane = tid & 63;
    const int wave = tid >> 6;  // 0..7
    const int wm = wave >> 2;   // 0..1  (M half)
    const int wn = wave & 3;    // 0..3  (N quarter)
    const int kh = lane >> 4;   // 0..3
    const int lrow = lane & 15;
    const int bi = blockIdx.x >> 4;
    const int bj = blockIdx.x & 15;
    const int rowBase = bi * BM2;
    const int colBase = bj * BM2;

    const short* gbase = (const short*)Ebf;

    // stage half h of K-tile kt into buf (2 x global_load_lds per thread)
    auto stage = [&](int kt, int buf, int h) {
        int gr0 = (h < 2 ? rowBase : colBase) + ((h & 1) ? 128 : 0);
#pragma unroll
        for (int q = 0; q < 2; ++q) {
            int i = q * 512 + tid;       // 16B chunk index in half (0..1023)
            int r = i >> 3;              // row in half
            int lc = (i & 7) ^ (r & 7);  // logical chunk for this physical slot
            const short* g = gbase + (size_t)(gr0 + r) * D + kt * BK2 + lc * 8;
            gload_lds16(g, &lds[buf][h][i * 8]);
        }
    };

    auto ldA = [&](int buf, int ah, s16x8 (&a)[4][2]) {
#pragma unroll
        for (int mi = 0; mi < 4; ++mi)
#pragma unroll
            for (int ks = 0; ks < 2; ++ks) {
                int rh = ah * 64 + mi * 16 + lrow;
                int c = ks * 4 + kh;
                a[mi][ks] = *(const s16x8*)&lds[buf][wm][rh * 64 + ((c ^ (rh & 7)) << 3)];
            }
    };
    auto ldB = [&](int buf, int nih, s16x8 (&bf)[2][2]) {
        int h = 2 + (wn >> 1);
#pragma unroll
        for (int ni = 0; ni < 2; ++ni)
#pragma unroll
            for (int ks = 0; ks < 2; ++ks) {
                int rh = (wn & 1) * 64 + nih * 32 + ni * 16 + lrow;
                int c = ks * 4 + kh;
                bf[ni][ks] = *(const s16x8*)&lds[buf][h][rh * 64 + ((c ^ (rh & 7)) << 3)];
            }
    };

    f32x4 acc[8][4];
#pragma unroll
    for (int i = 0; i < 8; ++i)
#pragma unroll
        for (int j = 0; j < 4; ++j) acc[i][j] = (f32x4)(0.f);

    s16x8 aq[4][2];
    s16x8 bq[2][2][2];

    // prologue: tile0 all 4 halves + tile1 B halves; wait tile0, leave tile1.B flying
    stage(0, 0, 0);
    stage(0, 0, 1);
    stage(0, 0, 2);
    stage(0, 0, 3);
    stage(1, 1, 2);
    stage(1, 1, 3);
    asm volatile("s_waitcnt vmcnt(4)" ::: "memory");
    __builtin_amdgcn_s_barrier();

    for (int u = 0; u < NK2; ++u) {
        const int bp = u & 1;
        // ---- P1: read A-q0 (8) + B-q0 (4); stage (u+1).A_lo ----
        ldA(bp, 0, aq);
        ldB(bp, 0, bq[0]);
        if (u + 1 < NK2) stage(u + 1, bp ^ 1, 0);
        __builtin_amdgcn_s_barrier();
        asm volatile("s_waitcnt lgkmcnt(0)" ::: "memory");
        __builtin_amdgcn_sched_barrier(0);
        doQ<0, 0>(acc, aq, bq);
        __builtin_amdgcn_s_barrier();
        // ---- P2: read B-q1 (4); stage (u+1).A_hi ----
        ldB(bp, 1, bq[1]);
        if (u + 1 < NK2) stage(u + 1, bp ^ 1, 1);
        __builtin_amdgcn_s_barrier();
        asm volatile("s_waitcnt lgkmcnt(0)" ::: "memory");
        __builtin_amdgcn_sched_barrier(0);
        doQ<0, 1>(acc, aq, bq);
        __builtin_amdgcn_s_barrier();
        // ---- P3: read A-q1 (8); stage (u+2).B_lo ----
        ldA(bp, 1, aq);
        if (u + 2 < NK2) stage(u + 2, bp, 2);
        __builtin_amdgcn_s_barrier();
        asm volatile("s_waitcnt lgkmcnt(0)" ::: "memory");
        __builtin_amdgcn_sched_barrier(0);
        doQ<1, 1>(acc, aq, bq);
        __builtin_amdgcn_s_barrier();
        // ---- P4 (reg-only MFMA): stage (u+2).B_hi; counted vmcnt; one barrier ----
        if (u + 2 < NK2) stage(u + 2, bp, 3);
        doQ<1, 0>(acc, aq, bq);
        if (u + 2 < NK2) {
            asm volatile("s_waitcnt vmcnt(4)" ::: "memory");  // (u+1) fully landed; (u+2).B_* fly
        } else if (u + 1 < NK2) {
            asm volatile("s_waitcnt vmcnt(0)" ::: "memory");  // tail drain (u=14)
        }
        __builtin_amdgcn_s_barrier();
    }

    // epilogue: exp + diag mask -> denomsum; label-masked sim row-sum -> lblsum;
    // diagonal sim -> selfsim.
    float lbm[4];
#pragma unroll
    for (int ni = 0; ni < 4; ++ni)
        lbm[ni] = (labels[colBase + wn * 64 + ni * 16 + lrow] == 0) ? 1.f : 0.f;

#pragma unroll
    for (int mi = 0; mi < 8; ++mi) {
        float rs[4] = {0.f, 0.f, 0.f, 0.f};
        float ps[4] = {0.f, 0.f, 0.f, 0.f};
#pragma unroll
        for (int ni = 0; ni < 4; ++ni) {
            int gcol = colBase + wn * 64 + ni * 16 + lrow;
#pragma unroll
            for (int r = 0; r < 4; ++r) {
                int grow = rowBase + wm * 128 + mi * 16 + kh * 4 + r;
                float sv = acc[mi][ni][r];
                float e = __expf(sv);
                if (grow == gcol) {
                    e = 0.f;
                    selfsim[grow] = sv;
                }
                rs[r] += e;
                ps[r] += sv * lbm[ni];
            }
        }
#pragma unroll
        for (int m = 1; m < 16; m <<= 1)
#pragma unroll
            for (int r = 0; r < 4; ++r) {
                rs[r] += __shfl_xor(rs[r], m, 64);
                ps[r] += __shfl_xor(ps[r], m, 64);
            }
        if (lrow == 0) {
#pragma unroll
            for (int r = 0; r < 4; ++r) {
                int grow = rowBase + wm * 128 + mi * 16 + kh * 4 + r;
                atomicAdd(&denomsum[grow], rs[r]);
                atomicAdd(&lblsum[grow], ps[r]);
            }
        }
    }
}

// K2: finalize scalar loss.
__global__ __launch_bounds__(1024) void finalize_kernel(const int* __restrict__ labels,
                                                        const float* __restrict__ denomsum,
                                                        const float* __restrict__ lblsum,
                                                        const float* __restrict__ selfsim,
                                                        float* __restrict__ out) {
    __shared__ int ncnt[16];
    __shared__ float tsum[16];
    int tid = threadIdx.x;
    int wv = tid >> 6, ln = tid & 63;

    int cnt = 0;
    for (int j = tid; j < B; j += 1024) cnt += (labels[j] == 0) ? 1 : 0;
    for (int m = 32; m; m >>= 1) cnt += __shfl_xor(cnt, m, 64);
    if (ln == 0) ncnt[wv] = cnt;
    __syncthreads();
    int n_normal = 0;
#pragma unroll
    for (int w = 0; w < 16; ++w) n_normal += ncnt[w];

    float local = 0.f;
    for (int i = tid; i < B; i += 1024) {
        if (labels[i] == 0) {
            int cntp = n_normal - 1;
            if (cntp > 0) {
                float possum = lblsum[i] - selfsim[i];  // remove j==i term (label_i==0 here)
                local += logf(denomsum[i]) - possum / (float)cntp;
            }
        }
    }
    for (int m = 32; m; m >>= 1) local += __shfl_xor(local, m, 64);
    if (ln == 0) tsum[wv] = local;
    __syncthreads();
    if (tid == 0) {
        float t = 0.f;
#pragma unroll
        for (int w = 0; w < 16; ++w) t += tsum[w];
        out[0] = (n_normal > 0) ? t / (float)n_normal : 0.f;
    }
}

extern "C" void kernel_launch(void* const* d_in, const int* in_sizes, int n_in,
                              void* d_out, int out_size, void* d_ws, size_t ws_size,
                              hipStream_t stream) {
    const float* E = (const float*)d_in[0];
    const int* labels = (const int*)d_in[1];
    float* out = (float*)d_out;

    char* ws = (char*)d_ws;
    size_t off = 0;
    unsigned short* Ebf = (unsigned short*)(ws + off);
    off += (size_t)B * D * 2;  // 8 MB
    float* denomsum = (float*)(ws + off);
    off += B * sizeof(float);
    float* lblsum = (float*)(ws + off);
    off += B * sizeof(float);
    float* selfsim = (float*)(ws + off);
    off += B * sizeof(float);

    prep_kernel<<<2048, 256, 0, stream>>>(E, Ebf, denomsum, lblsum);
    simexp8_kernel<<<NB2 * NB2, 512, 0, stream>>>(Ebf, labels, denomsum, lblsum, selfsim);
    finalize_kernel<<<1, 1024, 0, stream>>>(labels, denomsum, lblsum, selfsim, out);
}

// Round 14
// 55.207 us; speedup vs baseline: 1.0638x; 1.0213x over previous
//
#include <hip/hip_runtime.h>
#include <hip/hip_bf16.h>
#include <math.h>

#define B 4096
#define D 1024

// ---- 8-phase 256^2 simexp geometry (R6-verified best configuration) ----
#define BM2 256
#define BK2 64
#define NK2 (D / BK2)   // 16 K-tiles
#define NB2 (B / BM2)   // 16 -> grid 256 blocks

typedef float f32x4 __attribute__((ext_vector_type(4)));
typedef short s16x8 __attribute__((ext_vector_type(8)));

__device__ inline void gload_lds16(const void* g, void* l) {
    __builtin_amdgcn_global_load_lds(
        (const __attribute__((address_space(1))) void*)g,
        (__attribute__((address_space(3))) void*)l, 16, 0, 0);
}

// K0: fp32 -> bf16 convert; also zero denomsum/lblsum accumulators.
__global__ __launch_bounds__(256) void prep_kernel(const float* __restrict__ E,
                                                   unsigned short* __restrict__ Ebf,
                                                   float* __restrict__ denomsum,
                                                   float* __restrict__ lblsum) {
    int idx = blockIdx.x * 256 + threadIdx.x;
    if (blockIdx.x < 16) denomsum[idx] = 0.f;
    else if (blockIdx.x < 32) lblsum[idx - 4096] = 0.f;
    const float4* src = (const float4*)E;
    const int n4 = B * D / 4;
    for (int i = idx; i < n4; i += gridDim.x * 256) {
        float4 v = src[i];
        __hip_bfloat16 b0 = __float2bfloat16(v.x);
        __hip_bfloat16 b1 = __float2bfloat16(v.y);
        __hip_bfloat16 b2 = __float2bfloat16(v.z);
        __hip_bfloat16 b3 = __float2bfloat16(v.w);
        ushort4 o;
        o.x = *reinterpret_cast<unsigned short*>(&b0);
        o.y = *reinterpret_cast<unsigned short*>(&b1);
        o.z = *reinterpret_cast<unsigned short*>(&b2);
        o.w = *reinterpret_cast<unsigned short*>(&b3);
        *reinterpret_cast<ushort4*>(&Ebf[i * 4]) = o;
    }
}

// MFMA quadrant: AH selects A rows half, NIH selects B cols half.
template <int AH, int NIH>
__device__ inline void doQ(f32x4 acc[8][4], const s16x8 aq[4][2], const s16x8 bq[2][2][2]) {
    __builtin_amdgcn_s_setprio(1);
#pragma unroll
    for (int mi = 0; mi < 4; ++mi)
#pragma unroll
        for (int ni = 0; ni < 2; ++ni)
#pragma unroll
            for (int ks = 0; ks < 2; ++ks)
                acc[AH * 4 + mi][NIH * 2 + ni] = __builtin_amdgcn_mfma_f32_16x16x32_bf16(
                    aq[mi][ks], bq[NIH][ni][ks], acc[AH * 4 + mi][NIH * 2 + ni], 0, 0, 0);
    __builtin_amdgcn_s_setprio(0);
}

// K1: 256^2 8-phase simexp.
//   denomsum[i] += sum_j exp(sim[i,j])   (diag masked)
//   lblsum[i]   += sum_j sim[i,j] * [label_j == 0]   (diag INCLUDED)
//   selfsim[i]   = sim[i,i]              (written by diagonal blocks)
// LDS halves: 0=A rows 0-127, 1=A rows 128-255, 2=B rows 0-127, 3=B rows 128-255.
// XOR chunk swizzle applied to global source (write side) and ds_read addr (read side).
// Stage schedule per tile u: P1:(u+1).A_lo  P2:(u+1).A_hi  P3:(u+2).B_lo  P4:(u+2).B_hi
//   (B halves are last read in P2, A halves in P3 -> each slot staged after its last reader.)
// One counted vmcnt(4) per tile at P4; drains to 0 only at u=14.
// K-loop fully unrolled (NK2=16): buffer index bp and all stage guards become
// compile-time constants -> all LDS read/write address arithmetic (loop-invariant
// per buffer) is hoisted; dynamic schedule is unchanged from the verified R6 state.
__global__ __launch_bounds__(512, 2) void simexp8_kernel(const unsigned short* __restrict__ Ebf,
                                                         const int* __restrict__ labels,
                                                         float* __restrict__ denomsum,
                                                         float* __restrict__ lblsum,
                                                         float* __restrict__ selfsim) {
    __shared__ short lds[2][4][128 * 64];  // 128 KiB
    const int tid = threadIdx.x;
    const int lane = tid & 63;
    const int wave = tid >> 6;  // 0..7
    const int wm = wave >> 2;   // 0..1  (M half)
    const int wn = wave & 3;    // 0..3  (N quarter)
    const int kh = lane >> 4;   // 0..3
    const int lrow = lane & 15;
    const int bi = blockIdx.x >> 4;
    const int bj = blockIdx.x & 15;
    const int rowBase = bi * BM2;
    const int colBase = bj * BM2;

    const short* gbase = (const short*)Ebf;

    // stage half h of K-tile kt into buf (2 x global_load_lds per thread)
    auto stage = [&](int kt, int buf, int h) {
#pragma unroll
        for (int q = 0; q < 2; ++q) {
            int i = q * 512 + tid;       // 16B chunk index in half (0..1023)
            int r = i >> 3;              // row in half
            int lc = (i & 7) ^ (r & 7);  // logical chunk for this physical slot
            int gr0 = (h < 2 ? rowBase : colBase) + ((h & 1) ? 128 : 0);
            const short* g = gbase + (size_t)(gr0 + r) * D + kt * BK2 + lc * 8;
            gload_lds16(g, &lds[buf][h][i * 8]);
        }
    };

    auto ldA = [&](int buf, int ah, s16x8 (&a)[4][2]) {
#pragma unroll
        for (int mi = 0; mi < 4; ++mi)
#pragma unroll
            for (int ks = 0; ks < 2; ++ks) {
                int rh = ah * 64 + mi * 16 + lrow;
                int c = ks * 4 + kh;
                a[mi][ks] = *(const s16x8*)&lds[buf][wm][rh * 64 + ((c ^ (rh & 7)) << 3)];
            }
    };
    auto ldB = [&](int buf, int nih, s16x8 (&bf)[2][2]) {
        int h = 2 + (wn >> 1);
#pragma unroll
        for (int ni = 0; ni < 2; ++ni)
#pragma unroll
            for (int ks = 0; ks < 2; ++ks) {
                int rh = (wn & 1) * 64 + nih * 32 + ni * 16 + lrow;
                int c = ks * 4 + kh;
                bf[ni][ks] = *(const s16x8*)&lds[buf][h][rh * 64 + ((c ^ (rh & 7)) << 3)];
            }
    };

    f32x4 acc[8][4];
#pragma unroll
    for (int i = 0; i < 8; ++i)
#pragma unroll
        for (int j = 0; j < 4; ++j) acc[i][j] = (f32x4)(0.f);

    s16x8 aq[4][2];
    s16x8 bq[2][2][2];

    // prologue: tile0 all 4 halves + tile1 B halves; wait tile0, leave tile1.B flying
    stage(0, 0, 0);
    stage(0, 0, 1);
    stage(0, 0, 2);
    stage(0, 0, 3);
    stage(1, 1, 2);
    stage(1, 1, 3);
    asm volatile("s_waitcnt vmcnt(4)" ::: "memory");
    __builtin_amdgcn_s_barrier();

#pragma unroll
    for (int u = 0; u < NK2; ++u) {
        const int bp = u & 1;
        // ---- P1: read A-q0 (8) + B-q0 (4); stage (u+1).A_lo ----
        ldA(bp, 0, aq);
        ldB(bp, 0, bq[0]);
        if (u + 1 < NK2) stage(u + 1, bp ^ 1, 0);
        __builtin_amdgcn_s_barrier();
        asm volatile("s_waitcnt lgkmcnt(0)" ::: "memory");
        __builtin_amdgcn_sched_barrier(0);
        doQ<0, 0>(acc, aq, bq);
        __builtin_amdgcn_s_barrier();
        // ---- P2: read B-q1 (4); stage (u+1).A_hi ----
        ldB(bp, 1, bq[1]);
        if (u + 1 < NK2) stage(u + 1, bp ^ 1, 1);
        __builtin_amdgcn_s_barrier();
        asm volatile("s_waitcnt lgkmcnt(0)" ::: "memory");
        __builtin_amdgcn_sched_barrier(0);
        doQ<0, 1>(acc, aq, bq);
        __builtin_amdgcn_s_barrier();
        // ---- P3: read A-q1 (8); stage (u+2).B_lo ----
        ldA(bp, 1, aq);
        if (u + 2 < NK2) stage(u + 2, bp, 2);
        __builtin_amdgcn_s_barrier();
        asm volatile("s_waitcnt lgkmcnt(0)" ::: "memory");
        __builtin_amdgcn_sched_barrier(0);
        doQ<1, 1>(acc, aq, bq);
        __builtin_amdgcn_s_barrier();
        // ---- P4 (reg-only MFMA): stage (u+2).B_hi; counted vmcnt; one barrier ----
        if (u + 2 < NK2) stage(u + 2, bp, 3);
        doQ<1, 0>(acc, aq, bq);
        if (u + 2 < NK2) {
            asm volatile("s_waitcnt vmcnt(4)" ::: "memory");  // (u+1) fully landed; (u+2).B_* fly
        } else if (u + 1 < NK2) {
            asm volatile("s_waitcnt vmcnt(0)" ::: "memory");  // tail drain (u=14)
        }
        __builtin_amdgcn_s_barrier();
    }

    // epilogue: exp + diag mask -> denomsum; label-masked sim row-sum -> lblsum;
    // diagonal sim -> selfsim.
    float lbm[4];
#pragma unroll
    for (int ni = 0; ni < 4; ++ni)
        lbm[ni] = (labels[colBase + wn * 64 + ni * 16 + lrow] == 0) ? 1.f : 0.f;

#pragma unroll
    for (int mi = 0; mi < 8; ++mi) {
        float rs[4] = {0.f, 0.f, 0.f, 0.f};
        float ps[4] = {0.f, 0.f, 0.f, 0.f};
#pragma unroll
        for (int ni = 0; ni < 4; ++ni) {
            int gcol = colBase + wn * 64 + ni * 16 + lrow;
#pragma unroll
            for (int r = 0; r < 4; ++r) {
                int grow = rowBase + wm * 128 + mi * 16 + kh * 4 + r;
                float sv = acc[mi][ni][r];
                float e = __expf(sv);
                if (grow == gcol) {
                    e = 0.f;
                    selfsim[grow] = sv;
                }
                rs[r] += e;
                ps[r] += sv * lbm[ni];
            }
        }
#pragma unroll
        for (int m = 1; m < 16; m <<= 1)
#pragma unroll
            for (int r = 0; r < 4; ++r) {
                rs[r] += __shfl_xor(rs[r], m, 64);
                ps[r] += __shfl_xor(ps[r], m, 64);
            }
        if (lrow == 0) {
#pragma unroll
            for (int r = 0; r < 4; ++r) {
                int grow = rowBase + wm * 128 + mi * 16 + kh * 4 + r;
                atomicAdd(&denomsum[grow], rs[r]);
                atomicAdd(&lblsum[grow], ps[r]);
            }
        }
    }
}

// K2: finalize scalar loss.
__global__ __launch_bounds__(1024) void finalize_kernel(const int* __restrict__ labels,
                                                        const float* __restrict__ denomsum,
                                                        const float* __restrict__ lblsum,
                                                        const float* __restrict__ selfsim,
                                                        float* __restrict__ out) {
    __shared__ int ncnt[16];
    __shared__ float tsum[16];
    int tid = threadIdx.x;
    int wv = tid >> 6, ln = tid & 63;

    int cnt = 0;
    for (int j = tid; j < B; j += 1024) cnt += (labels[j] == 0) ? 1 : 0;
    for (int m = 32; m; m >>= 1) cnt += __shfl_xor(cnt, m, 64);
    if (ln == 0) ncnt[wv] = cnt;
    __syncthreads();
    int n_normal = 0;
#pragma unroll
    for (int w = 0; w < 16; ++w) n_normal += ncnt[w];

    float local = 0.f;
    for (int i = tid; i < B; i += 1024) {
        if (labels[i] == 0) {
            int cntp = n_normal - 1;
            if (cntp > 0) {
                float possum = lblsum[i] - selfsim[i];  // remove j==i term (label_i==0 here)
                local += logf(denomsum[i]) - possum / (float)cntp;
            }
        }
    }
    for (int m = 32; m; m >>= 1) local += __shfl_xor(local, m, 64);
    if (ln == 0) tsum[wv] = local;
    __syncthreads();
    if (tid == 0) {
        float t = 0.f;
#pragma unroll
        for (int w = 0; w < 16; ++w) t += tsum[w];
        out[0] = (n_normal > 0) ? t / (float)n_normal : 0.f;
    }
}

extern "C" void kernel_launch(void* const* d_in, const int* in_sizes, int n_in,
                              void* d_out, int out_size, void* d_ws, size_t ws_size,
                              hipStream_t stream) {
    const float* E = (const float*)d_in[0];
    const int* labels = (const int*)d_in[1];
    float* out = (float*)d_out;

    char* ws = (char*)d_ws;
    size_t off = 0;
    unsigned short* Ebf = (unsigned short*)(ws + off);
    off += (size_t)B * D * 2;  // 8 MB
    float* denomsum = (float*)(ws + off);
    off += B * sizeof(float);
    float* lblsum = (float*)(ws + off);
    off += B * sizeof(float);
    float* selfsim = (float*)(ws + off);
    off += B * sizeof(float);

    prep_kernel<<<2048, 256, 0, stream>>>(E, Ebf, denomsum, lblsum);
    simexp8_kernel<<<NB2 * NB2, 512, 0, stream>>>(Ebf, labels, denomsum, lblsum, selfsim);
    finalize_kernel<<<1, 1024, 0, stream>>>(labels, denomsum, lblsum, selfsim, out);
}

// Round 15
// 54.389 us; speedup vs baseline: 1.0798x; 1.0150x over previous
//
#include <hip/hip_runtime.h>
#include <hip/hip_bf16.h>
#include <math.h>

#define B 4096
#define D 1024

// ---- 8-phase 256^2 simexp geometry (R14-verified best configuration) ----
#define BM2 256
#define BK2 64
#define NK2 (D / BK2)   // 16 K-tiles
#define NB2 (B / BM2)   // 16 -> grid 256 blocks

typedef float f32x4 __attribute__((ext_vector_type(4)));
typedef short s16x8 __attribute__((ext_vector_type(8)));

__device__ inline void gload_lds16(const void* g, void* l) {
    __builtin_amdgcn_global_load_lds(
        (const __attribute__((address_space(1))) void*)g,
        (__attribute__((address_space(3))) void*)l, 16, 0, 0);
}

// K0: fp32 -> bf16 convert; zero denomsum/lblsum accumulators and out[0].
__global__ __launch_bounds__(256) void prep_kernel(const float* __restrict__ E,
                                                   unsigned short* __restrict__ Ebf,
                                                   float* __restrict__ denomsum,
                                                   float* __restrict__ lblsum,
                                                   float* __restrict__ out) {
    int idx = blockIdx.x * 256 + threadIdx.x;
    if (blockIdx.x < 16) denomsum[idx] = 0.f;
    else if (blockIdx.x < 32) lblsum[idx - 4096] = 0.f;
    else if (blockIdx.x == 32 && threadIdx.x == 0) out[0] = 0.f;
    const float4* src = (const float4*)E;
    const int n4 = B * D / 4;
    for (int i = idx; i < n4; i += gridDim.x * 256) {
        float4 v = src[i];
        __hip_bfloat16 b0 = __float2bfloat16(v.x);
        __hip_bfloat16 b1 = __float2bfloat16(v.y);
        __hip_bfloat16 b2 = __float2bfloat16(v.z);
        __hip_bfloat16 b3 = __float2bfloat16(v.w);
        ushort4 o;
        o.x = *reinterpret_cast<unsigned short*>(&b0);
        o.y = *reinterpret_cast<unsigned short*>(&b1);
        o.z = *reinterpret_cast<unsigned short*>(&b2);
        o.w = *reinterpret_cast<unsigned short*>(&b3);
        *reinterpret_cast<ushort4*>(&Ebf[i * 4]) = o;
    }
}

// MFMA quadrant: AH selects A rows half, NIH selects B cols half.
template <int AH, int NIH>
__device__ inline void doQ(f32x4 acc[8][4], const s16x8 aq[4][2], const s16x8 bq[2][2][2]) {
    __builtin_amdgcn_s_setprio(1);
#pragma unroll
    for (int mi = 0; mi < 4; ++mi)
#pragma unroll
        for (int ni = 0; ni < 2; ++ni)
#pragma unroll
            for (int ks = 0; ks < 2; ++ks)
                acc[AH * 4 + mi][NIH * 2 + ni] = __builtin_amdgcn_mfma_f32_16x16x32_bf16(
                    aq[mi][ks], bq[NIH][ni][ks], acc[AH * 4 + mi][NIH * 2 + ni], 0, 0, 0);
    __builtin_amdgcn_s_setprio(0);
}

// K1: 256^2 8-phase simexp (BYTE-FROZEN from R14 — verified best).
//   denomsum[i] += sum_j exp(sim[i,j])   (diag masked)
//   lblsum[i]   += sum_j sim[i,j] * [label_j == 0]   (diag INCLUDED)
//   selfsim[i]   = sim[i,i]              (written by diagonal blocks)
__global__ __launch_bounds__(512, 2) void simexp8_kernel(const unsigned short* __restrict__ Ebf,
                                                         const int* __restrict__ labels,
                                                         float* __restrict__ denomsum,
                                                         float* __restrict__ lblsum,
                                                         float* __restrict__ selfsim) {
    __shared__ short lds[2][4][128 * 64];  // 128 KiB
    const int tid = threadIdx.x;
    const int lane = tid & 63;
    const int wave = tid >> 6;  // 0..7
    const int wm = wave >> 2;   // 0..1  (M half)
    const int wn = wave & 3;    // 0..3  (N quarter)
    const int kh = lane >> 4;   // 0..3
    const int lrow = lane & 15;
    const int bi = blockIdx.x >> 4;
    const int bj = blockIdx.x & 15;
    const int rowBase = bi * BM2;
    const int colBase = bj * BM2;

    const short* gbase = (const short*)Ebf;

    auto stage = [&](int kt, int buf, int h) {
#pragma unroll
        for (int q = 0; q < 2; ++q) {
            int i = q * 512 + tid;       // 16B chunk index in half (0..1023)
            int r = i >> 3;              // row in half
            int lc = (i & 7) ^ (r & 7);  // logical chunk for this physical slot
            int gr0 = (h < 2 ? rowBase : colBase) + ((h & 1) ? 128 : 0);
            const short* g = gbase + (size_t)(gr0 + r) * D + kt * BK2 + lc * 8;
            gload_lds16(g, &lds[buf][h][i * 8]);
        }
    };

    auto ldA = [&](int buf, int ah, s16x8 (&a)[4][2]) {
#pragma unroll
        for (int mi = 0; mi < 4; ++mi)
#pragma unroll
            for (int ks = 0; ks < 2; ++ks) {
                int rh = ah * 64 + mi * 16 + lrow;
                int c = ks * 4 + kh;
                a[mi][ks] = *(const s16x8*)&lds[buf][wm][rh * 64 + ((c ^ (rh & 7)) << 3)];
            }
    };
    auto ldB = [&](int buf, int nih, s16x8 (&bf)[2][2]) {
        int h = 2 + (wn >> 1);
#pragma unroll
        for (int ni = 0; ni < 2; ++ni)
#pragma unroll
            for (int ks = 0; ks < 2; ++ks) {
                int rh = (wn & 1) * 64 + nih * 32 + ni * 16 + lrow;
                int c = ks * 4 + kh;
                bf[ni][ks] = *(const s16x8*)&lds[buf][h][rh * 64 + ((c ^ (rh & 7)) << 3)];
            }
    };

    f32x4 acc[8][4];
#pragma unroll
    for (int i = 0; i < 8; ++i)
#pragma unroll
        for (int j = 0; j < 4; ++j) acc[i][j] = (f32x4)(0.f);

    s16x8 aq[4][2];
    s16x8 bq[2][2][2];

    // prologue: tile0 all 4 halves + tile1 B halves; wait tile0, leave tile1.B flying
    stage(0, 0, 0);
    stage(0, 0, 1);
    stage(0, 0, 2);
    stage(0, 0, 3);
    stage(1, 1, 2);
    stage(1, 1, 3);
    asm volatile("s_waitcnt vmcnt(4)" ::: "memory");
    __builtin_amdgcn_s_barrier();

#pragma unroll
    for (int u = 0; u < NK2; ++u) {
        const int bp = u & 1;
        // ---- P1: read A-q0 (8) + B-q0 (4); stage (u+1).A_lo ----
        ldA(bp, 0, aq);
        ldB(bp, 0, bq[0]);
        if (u + 1 < NK2) stage(u + 1, bp ^ 1, 0);
        __builtin_amdgcn_s_barrier();
        asm volatile("s_waitcnt lgkmcnt(0)" ::: "memory");
        __builtin_amdgcn_sched_barrier(0);
        doQ<0, 0>(acc, aq, bq);
        __builtin_amdgcn_s_barrier();
        // ---- P2: read B-q1 (4); stage (u+1).A_hi ----
        ldB(bp, 1, bq[1]);
        if (u + 1 < NK2) stage(u + 1, bp ^ 1, 1);
        __builtin_amdgcn_s_barrier();
        asm volatile("s_waitcnt lgkmcnt(0)" ::: "memory");
        __builtin_amdgcn_sched_barrier(0);
        doQ<0, 1>(acc, aq, bq);
        __builtin_amdgcn_s_barrier();
        // ---- P3: read A-q1 (8); stage (u+2).B_lo ----
        ldA(bp, 1, aq);
        if (u + 2 < NK2) stage(u + 2, bp, 2);
        __builtin_amdgcn_s_barrier();
        asm volatile("s_waitcnt lgkmcnt(0)" ::: "memory");
        __builtin_amdgcn_sched_barrier(0);
        doQ<1, 1>(acc, aq, bq);
        __builtin_amdgcn_s_barrier();
        // ---- P4 (reg-only MFMA): stage (u+2).B_hi; counted vmcnt; one barrier ----
        if (u + 2 < NK2) stage(u + 2, bp, 3);
        doQ<1, 0>(acc, aq, bq);
        if (u + 2 < NK2) {
            asm volatile("s_waitcnt vmcnt(4)" ::: "memory");
        } else if (u + 1 < NK2) {
            asm volatile("s_waitcnt vmcnt(0)" ::: "memory");
        }
        __builtin_amdgcn_s_barrier();
    }

    // epilogue: exp + diag mask -> denomsum; label-masked sim row-sum -> lblsum;
    // diagonal sim -> selfsim.
    float lbm[4];
#pragma unroll
    for (int ni = 0; ni < 4; ++ni)
        lbm[ni] = (labels[colBase + wn * 64 + ni * 16 + lrow] == 0) ? 1.f : 0.f;

#pragma unroll
    for (int mi = 0; mi < 8; ++mi) {
        float rs[4] = {0.f, 0.f, 0.f, 0.f};
        float ps[4] = {0.f, 0.f, 0.f, 0.f};
#pragma unroll
        for (int ni = 0; ni < 4; ++ni) {
            int gcol = colBase + wn * 64 + ni * 16 + lrow;
#pragma unroll
            for (int r = 0; r < 4; ++r) {
                int grow = rowBase + wm * 128 + mi * 16 + kh * 4 + r;
                float sv = acc[mi][ni][r];
                float e = __expf(sv);
                if (grow == gcol) {
                    e = 0.f;
                    selfsim[grow] = sv;
                }
                rs[r] += e;
                ps[r] += sv * lbm[ni];
            }
        }
#pragma unroll
        for (int m = 1; m < 16; m <<= 1)
#pragma unroll
            for (int r = 0; r < 4; ++r) {
                rs[r] += __shfl_xor(rs[r], m, 64);
                ps[r] += __shfl_xor(ps[r], m, 64);
            }
        if (lrow == 0) {
#pragma unroll
            for (int r = 0; r < 4; ++r) {
                int grow = rowBase + wm * 128 + mi * 16 + kh * 4 + r;
                atomicAdd(&denomsum[grow], rs[r]);
                atomicAdd(&lblsum[grow], ps[r]);
            }
        }
    }
}

// K2: finalize scalar loss — 16 blocks, each owns 256 rows; per-block partial
// atomicAdd into out (zeroed by prep). n_normal recomputed per block (L2-hot labels).
__global__ __launch_bounds__(256) void finalize_kernel(const int* __restrict__ labels,
                                                       const float* __restrict__ denomsum,
                                                       const float* __restrict__ lblsum,
                                                       const float* __restrict__ selfsim,
                                                       float* __restrict__ out) {
    __shared__ int ncnt[4];
    __shared__ float tsum[4];
    int tid = threadIdx.x;
    int wv = tid >> 6, ln = tid & 63;

    int cnt = 0;
    for (int j = tid; j < B; j += 256) cnt += (labels[j] == 0) ? 1 : 0;
    for (int m = 32; m; m >>= 1) cnt += __shfl_xor(cnt, m, 64);
    if (ln == 0) ncnt[wv] = cnt;
    __syncthreads();
    int n_normal = ncnt[0] + ncnt[1] + ncnt[2] + ncnt[3];

    int i = blockIdx.x * 256 + tid;
    float local = 0.f;
    if (labels[i] == 0 && n_normal > 1) {
        float possum = lblsum[i] - selfsim[i];  // remove j==i term (label_i==0 here)
        local = logf(denomsum[i]) - possum / (float)(n_normal - 1);
    }
    for (int m = 32; m; m >>= 1) local += __shfl_xor(local, m, 64);
    if (ln == 0) tsum[wv] = local;
    __syncthreads();
    if (tid == 0 && n_normal > 0) {
        float t = (tsum[0] + tsum[1] + tsum[2] + tsum[3]) / (float)n_normal;
        atomicAdd(out, t);
    }
}

extern "C" void kernel_launch(void* const* d_in, const int* in_sizes, int n_in,
                              void* d_out, int out_size, void* d_ws, size_t ws_size,
                              hipStream_t stream) {
    const float* E = (const float*)d_in[0];
    const int* labels = (const int*)d_in[1];
    float* out = (float*)d_out;

    char* ws = (char*)d_ws;
    size_t off = 0;
    unsigned short* Ebf = (unsigned short*)(ws + off);
    off += (size_t)B * D * 2;  // 8 MB
    float* denomsum = (float*)(ws + off);
    off += B * sizeof(float);
    float* lblsum = (float*)(ws + off);
    off += B * sizeof(float);
    float* selfsim = (float*)(ws + off);
    off += B * sizeof(float);

    prep_kernel<<<2048, 256, 0, stream>>>(E, Ebf, denomsum, lblsum, out);
    simexp8_kernel<<<NB2 * NB2, 512, 0, stream>>>(Ebf, labels, denomsum, lblsum, selfsim);
    finalize_kernel<<<B / 256, 256, 0, stream>>>(labels, denomsum, lblsum, selfsim, out);
}